// Round 6
// baseline (187.781 us; speedup 1.0000x reference)
//
#include <hip/hip_runtime.h>
#include <hip/hip_bf16.h>

// Problem constants (fixed by setup_inputs)
#define B_SZ 8
#define H_SZ 32     // image rows
#define W_SZ 64     // image cols
#define N_SZ 2048   // H*W
#define C_SZ 512
#define NH 8        // heads
#define HD 64       // head dim
// window 7x11 -> +-3 rows, +-5 cols

using u16 = unsigned short;
typedef __attribute__((ext_vector_type(8))) short s16x8;
typedef __attribute__((ext_vector_type(4))) float f32x4;

__device__ __forceinline__ float bf2f(u16 u) {
    union { unsigned int i; float f; } c; c.i = ((unsigned int)u) << 16; return c.f;
}
__device__ __forceinline__ u16 f2bf(float f) {
    union { float f; unsigned int i; } c; c.f = f;
    unsigned int r = c.i + 0x7fffu + ((c.i >> 16) & 1u);  // RNE
    return (u16)(r >> 16);
}

// async global->LDS, 16B per lane; LDS dest must be wave-uniform base + lane*16
#define GLL16(gp, lp) __builtin_amdgcn_global_load_lds( \
    (const __attribute__((address_space(1))) unsigned int*)(gp), \
    (__attribute__((address_space(3))) unsigned int*)(lp), 16, 0, 0)

// XOR-swizzled 64-elem rows: row = 8 chunks of 8 bf16 (16B); data chunk c of row r
// lives at slot position c ^ (r&7).  Conflict-free ds_read_b128 across l16 lanes.
__device__ __forceinline__ int lds_off(int row, int chunk) {
    return (row * 8 + (chunk ^ (row & 7))) * 8;   // element offset
}

// ---------------- fused fp32 -> bf16 convert (x, qkv_w [q-rows scaled], proj_w) ----
#define NX4 2097152   // x float4 count (16384*512/4)
#define NQ4 196608    // qkv_w float4 count
#define NP4 65536     // proj_w float4 count
__global__ __launch_bounds__(256)
void conv_all(const float* __restrict__ x, const float* __restrict__ qw,
              const float* __restrict__ pw, u16* __restrict__ xb,
              u16* __restrict__ qwb, u16* __restrict__ pwb)
{
    const int i = blockIdx.x * 256 + threadIdx.x;
    const float* src; u16* dst; int idx; float sc = 1.0f;
    if (i < NX4)             { src = x;  dst = xb;  idx = i; }
    else if (i < NX4 + NQ4)  { src = qw; dst = qwb; idx = i - NX4;
                               if (idx < 65536) sc = 0.125f; }  // q-rows: fold 64^-0.5
    else                     { src = pw; dst = pwb; idx = i - NX4 - NQ4; }
    const float4 v = ((const float4*)src)[idx];
    ushort4 o = { f2bf(v.x * sc), f2bf(v.y * sc), f2bf(v.z * sc), f2bf(v.w * sc) };
    ((ushort4*)dst)[idx] = o;
}

// ---------------- MFMA GEMM: C[m,n] = sum_k A[m,k]*Bw[n,k] (bf16, K-contig) ------
// 128xNT tile, BK=64, swizzled LDS. 4 waves in 2x2.
// Operand-swap trick: a K-contiguous row-major fragment is valid as either MFMA
// operand; mfma(fw,fx) yields D[weight][token] so the 4 acc regs are d-consecutive
// -> vector stores.  Used for q/k (MODE 0, n0<1024) and proj (MODE 1).
// V blocks (n0>=1024) keep D[token][weight] (regs token-consecutive) for the
// transposed [bh][d][n] store.
template<int MODE, int NT>
__global__ __launch_bounds__(256)
void gemm_mfma(const u16* __restrict__ A, const u16* __restrict__ Bw,
               const float* __restrict__ bias,
               u16* __restrict__ q_ws, u16* __restrict__ k_ws, u16* __restrict__ v_ws,
               float* __restrict__ outp, int K)
{
    constexpr int NJ = (NT == 128) ? 4 : 2;   // 16-row weight tiles per wave
    __shared__ u16 As[128 * 64];
    __shared__ u16 Bs[NT * 64];
    const int t    = threadIdx.x;
    const int m0   = blockIdx.x * 128;
    const int n0   = blockIdx.y * NT;
    const int wave = t >> 6, lane = t & 63;
    const int wm   = (wave >> 1) << 6;            // token (m) offset of wave
    const int wn   = (wave & 1) * (NJ * 16);      // weight (n) offset of wave
    const int l16  = lane & 15, quad = lane >> 4;
    const int srow = t >> 3;                    // staging row 0..31 (per 32-row group)
    const int sch  = (t & 7) ^ (srow & 7);      // swizzled data chunk for this slot

    constexpr int AD0 = (MODE == 0) ? 4 : 2;
    f32x4 acc[AD0][4] = {};

    for (int k0 = 0; k0 < K; k0 += 64) {
        __syncthreads();
        #pragma unroll
        for (int g = 0; g < 4; ++g)
            GLL16(A + (size_t)(m0 + 32 * g + srow) * K + k0 + sch * 8,
                  &As[g * 2048 + t * 8]);
        #pragma unroll
        for (int g = 0; g < NT / 32; ++g)
            GLL16(Bw + (size_t)(n0 + 32 * g + srow) * K + k0 + sch * 8,
                  &Bs[g * 2048 + t * 8]);
        __syncthreads();

        s16x8 fx[4][2], fw[NJ][2];
        #pragma unroll
        for (int i = 0; i < 4; ++i) {
            const int R = wm + 16 * i + l16;
            fx[i][0] = *(const s16x8*)&As[lds_off(R, quad)];
            fx[i][1] = *(const s16x8*)&As[lds_off(R, 4 + quad)];
        }
        #pragma unroll
        for (int j = 0; j < NJ; ++j) {
            const int R = wn + 16 * j + l16;
            fw[j][0] = *(const s16x8*)&Bs[lds_off(R, quad)];
            fw[j][1] = *(const s16x8*)&Bs[lds_off(R, 4 + quad)];
        }
        if (MODE == 1 || n0 < 1024) {
            // swapped: acc[w][x] = D[weight][token]
            #pragma unroll
            for (int w = 0; w < AD0; ++w)
                #pragma unroll
                for (int x = 0; x < 4; ++x) {
                    acc[w][x] = __builtin_amdgcn_mfma_f32_16x16x32_bf16(fw[w][0], fx[x][0], acc[w][x], 0, 0, 0);
                    acc[w][x] = __builtin_amdgcn_mfma_f32_16x16x32_bf16(fw[w][1], fx[x][1], acc[w][x], 0, 0, 0);
                }
        } else {
            // V blocks: acc[x][w] = D[token][weight]
            #pragma unroll
            for (int x = 0; x < 4; ++x)
                #pragma unroll
                for (int w = 0; w < 4; ++w) {
                    acc[x][w] = __builtin_amdgcn_mfma_f32_16x16x32_bf16(fx[x][0], fw[w][0], acc[x][w], 0, 0, 0);
                    acc[x][w] = __builtin_amdgcn_mfma_f32_16x16x32_bf16(fx[x][1], fw[w][1], acc[x][w], 0, 0, 0);
                }
        }
    }

    if (MODE == 0) {
        const int bb = m0 >> 11;                       // batch (block-uniform)
        if (n0 < 1024) {
            // q/k, swapped: row=weight (d), col=token.  d = 16w + quad*4 + r.
            const int h = ((n0 + wn) >> 6) & 7;        // wave-uniform head
            u16* T  = (n0 < 512) ? q_ws : k_ws;
            u16* tb = T + ((size_t)bb * NH + h) * (N_SZ * HD);
            const int nn0 = (m0 & 2047) + wm;
            const int dd0 = (quad << 2);
            #pragma unroll
            for (int w = 0; w < 4; ++w)
                #pragma unroll
                for (int x = 0; x < 4; ++x) {
                    const int nn = nn0 + 16 * x + l16;
                    ushort4 st = { f2bf(acc[w][x][0]), f2bf(acc[w][x][1]),
                                   f2bf(acc[w][x][2]), f2bf(acc[w][x][3]) };
                    *(ushort4*)(tb + (size_t)nn * HD + 16 * w + dd0) = st;
                }
        } else {
            // V, unswapped: regs are token-consecutive -> [bh][d][n] store
            const int nnb = (m0 & 2047) + wm + (quad << 2);
            #pragma unroll
            for (int w = 0; w < 4; ++w) {
                const int c = n0 - 1024 + wn + 16 * w + l16;   // v col 0..511
                const int h = c >> 6, dd = c & 63;
                u16* vp = v_ws + (((size_t)bb * NH + h) * HD + dd) * N_SZ + nnb;
                #pragma unroll
                for (int x = 0; x < 4; ++x) {
                    ushort4 st = { f2bf(acc[x][w][0]), f2bf(acc[x][w][1]),
                                   f2bf(acc[x][w][2]), f2bf(acc[x][w][3]) };
                    *(ushort4*)(vp + 16 * x) = st;
                }
            }
        }
    } else {
        // proj, swapped: 4 regs = 4 consecutive out channels -> float4 stores
        #pragma unroll
        for (int w = 0; w < 2; ++w) {
            const int cb = n0 + wn + 16 * w + (quad << 2);
            const float4 bv = *(const float4*)&bias[cb];
            #pragma unroll
            for (int x = 0; x < 4; ++x) {
                const int gm = m0 + wm + 16 * x + l16;
                float4 st = { acc[w][x][0] + bv.x, acc[w][x][1] + bv.y,
                              acc[w][x][2] + bv.z, acc[w][x][3] + bv.w };
                *(float4*)&outp[(size_t)gm * C_SZ + cb] = st;
            }
        }
    }
}

// ---------------- MFMA local attention: 2 image rows / block ----------------
// block = (bh, row-pair p): queries = rows 2p,2p+1 (128 q).  Wave w handles the
// 16-query span [16w,16w+16) in BOTH rows, key window [kb,kb+32),
// kb = clamp(16w-8,0,32).  PV uses the operand swap (O[d][q]) so the final store
// is 8 ushort4 instead of 32 scalar; l transposed across lanes via 8 shfls.
__global__ __launch_bounds__(256)
void attn_mfma(const u16* __restrict__ q_ws, const u16* __restrict__ k_ws,
               const u16* __restrict__ vt_ws, u16* __restrict__ o_ws)
{
    __shared__ u16 KV[2][64 * 64];   // [0]=K row, [1]=Vt row; Q staging at start
    __shared__ u16 Ps[4][16 * 40];   // per-wave P, [q16][key32], stride 40 elems

    const int t = threadIdx.x, wave = t >> 6, lane = t & 63;
    const int l16 = lane & 15, quad = lane >> 4;
    const int u  = blockIdx.x;
    const int p  = u & 15;           // row pair
    const int bh = u >> 4;
    const int r0 = 2 * p, r1 = 2 * p + 1;
    const size_t base = (size_t)bh * (N_SZ * HD);
    const int srow = t >> 3;
    const int sch  = (t & 7) ^ (srow & 7);

    // stage Q rows r0,r1 (128x64 = 16 KB) into KV, swizzled; extract frags
    const u16* qg = q_ws + base + (size_t)r0 * (64 * HD);
    u16* Qst = &KV[0][0];
    #pragma unroll
    for (int g = 0; g < 4; ++g)
        GLL16(qg + (size_t)(srow + 32 * g) * 64 + sch * 8, Qst + g * 2048 + t * 8);
    __syncthreads();

    s16x8 aQ[2][2];
    #pragma unroll
    for (int s = 0; s < 2; ++s) {
        const int Rq = 64 * s + 16 * wave + l16;
        aQ[s][0] = *(const s16x8*)&Qst[lds_off(Rq, quad)];
        aQ[s][1] = *(const s16x8*)&Qst[lds_off(Rq, 4 + quad)];
    }

    const int kb = min(max(16 * wave - 8, 0), 32);   // 0, 8, 24, 32

    f32x4 accO[2][4] = {};
    float lp[2][4] = {};

    const int hlo = (r0 - 3 < 0) ? 0 : r0 - 3;
    const int hhi = (r1 + 3 > H_SZ - 1) ? H_SZ - 1 : r1 + 3;

    for (int hh = hlo; hh <= hhi; ++hh) {
        __syncthreads();   // previous iter's reads (and Q extract) done
        const u16* kg = k_ws + base + (size_t)hh * (64 * HD);
        GLL16(kg + (size_t)srow        * 64 + sch * 8, &KV[0][t * 8]);
        GLL16(kg + (size_t)(srow + 32) * 64 + sch * 8, &KV[0][2048 + t * 8]);
        const u16* vg = vt_ws + base + (size_t)hh * 64;
        GLL16(vg + (size_t)srow        * N_SZ + sch * 8, &KV[1][t * 8]);
        GLL16(vg + (size_t)(srow + 32) * N_SZ + sch * 8, &KV[1][2048 + t * 8]);
        __syncthreads();

        // K/V frags for this wave's 32-key window
        s16x8 bK[2][2];
        #pragma unroll
        for (int j = 0; j < 2; ++j) {
            const int Rk = kb + 16 * j + l16;
            bK[j][0] = *(const s16x8*)&KV[0][lds_off(Rk, quad)];
            bK[j][1] = *(const s16x8*)&KV[0][lds_off(Rk, 4 + quad)];
        }
        s16x8 vf[4];
        #pragma unroll
        for (int j = 0; j < 4; ++j)
            vf[j] = *(const s16x8*)&KV[1][lds_off(16 * j + l16, (kb >> 3) + quad)];

        #pragma unroll
        for (int s = 0; s < 2; ++s) {
            const int dh = hh - (r0 + s);
            if (dh * dh > 9) continue;     // wave-uniform: row out of +-3 range
            f32x4 z[2] = {{0.f,0.f,0.f,0.f},{0.f,0.f,0.f,0.f}};
            #pragma unroll
            for (int j = 0; j < 2; ++j) {
                z[j] = __builtin_amdgcn_mfma_f32_16x16x32_bf16(aQ[s][0], bK[j][0], z[j], 0, 0, 0);
                z[j] = __builtin_amdgcn_mfma_f32_16x16x32_bf16(aQ[s][1], bK[j][1], z[j], 0, 0, 0);
            }
            #pragma unroll
            for (int j = 0; j < 2; ++j) {
                const int ww = kb + 16 * j + l16;   // key w-coord
                #pragma unroll
                for (int r = 0; r < 4; ++r) {
                    const int dw = ww - (16 * wave + quad * 4 + r);
                    const float pv = (dw * dw <= 25) ? __expf(z[j][r]) : 0.f;
                    const u16 pb = f2bf(pv);
                    lp[s][r] += bf2f(pb);
                    Ps[wave][(quad * 4 + r) * 40 + 16 * j + l16] = pb;
                }
            }
            // PV swapped: O[d][q] += V^T(d x key) . P^T(key x q)
            // A-frag = Vt rows (d, key-contig); B-frag = Ps rows (q, key-contig)
            s16x8 aP = *(const s16x8*)&Ps[wave][l16 * 40 + quad * 8];
            #pragma unroll
            for (int j = 0; j < 4; ++j)
                accO[s][j] = __builtin_amdgcn_mfma_f32_16x16x32_bf16(vf[j], aP, accO[s][j], 0, 0, 0);
        }
    }

    // reduce l across the 16 lanes sharing a quad-row (disjoint key subsets)
    #pragma unroll
    for (int s = 0; s < 2; ++s)
        #pragma unroll
        for (int r = 0; r < 4; ++r) {
            lp[s][r] += __shfl_xor(lp[s][r], 1);
            lp[s][r] += __shfl_xor(lp[s][r], 2);
            lp[s][r] += __shfl_xor(lp[s][r], 4);
            lp[s][r] += __shfl_xor(lp[s][r], 8);
        }

    // transpose l: this lane normalizes query q = l16 -> fetch from quad (l16>>2)
    const int srcl = (l16 >> 2) << 4;
    const int rr   = l16 & 3;
    float inv[2];
    #pragma unroll
    for (int s = 0; s < 2; ++s) {
        const float a0 = __shfl(lp[s][0], srcl);
        const float a1 = __shfl(lp[s][1], srcl);
        const float a2 = __shfl(lp[s][2], srcl);
        const float a3 = __shfl(lp[s][3], srcl);
        const float lq = (rr == 0) ? a0 : (rr == 1) ? a1 : (rr == 2) ? a2 : a3;
        inv[s] = 1.0f / lq;
    }

    // write O in (B, N, C) layout: row = query (col l16), 4 regs = 4 consecutive d
    const int bb = bh >> 3, h = bh & 7;
    #pragma unroll
    for (int s = 0; s < 2; ++s) {
        const int row = (r0 + s) * 64 + 16 * wave + l16;
        u16* ob = o_ws + ((size_t)bb * N_SZ + row) * C_SZ + h * 64 + (quad << 2);
        #pragma unroll
        for (int j = 0; j < 4; ++j) {
            ushort4 st = { f2bf(accO[s][j][0] * inv[s]), f2bf(accO[s][j][1] * inv[s]),
                           f2bf(accO[s][j][2] * inv[s]), f2bf(accO[s][j][3] * inv[s]) };
            *(ushort4*)(ob + 16 * j) = st;
        }
    }
}

extern "C" void kernel_launch(void* const* d_in, const int* in_sizes, int n_in,
                              void* d_out, int out_size, void* d_ws, size_t ws_size,
                              hipStream_t stream)
{
    const float* x      = (const float*)d_in[0];
    const float* qkv_w  = (const float*)d_in[1];
    const float* proj_w = (const float*)d_in[2];
    const float* proj_b = (const float*)d_in[3];
    float* outp = (float*)d_out;

    const size_t seg = (size_t)B_SZ * NH * N_SZ * HD;  // 8388608 elems
    u16* q_ws = (u16*)d_ws;
    u16* k_ws = q_ws + seg;
    u16* v_ws = k_ws + seg;      // transposed layout [bh][d][n]
    u16* o_ws = v_ws + seg;
    u16* xb   = o_ws + seg;                       // x as bf16 (8.4M elems)
    u16* qwb  = xb + (size_t)16384 * 512;         // qkv_w bf16 (786432)
    u16* pwb  = qwb + (size_t)1536 * 512;         // proj_w bf16 (262144)

    // one fused convert: (NX4+NQ4+NP4)/256 = 9216 blocks
    conv_all<<<9216, 256, 0, stream>>>(x, qkv_w, proj_w, xb, qwb, pwb);

    // QKV GEMM: M=16384, N=1536, K=512
    gemm_mfma<0, 128><<<dim3(128, 12), 256, 0, stream>>>(xb, qwb, nullptr,
                                                         q_ws, k_ws, v_ws, nullptr, C_SZ);
    // local attention, one block per (b,h,row-pair)
    attn_mfma<<<B_SZ * NH * (H_SZ / 2), 256, 0, stream>>>(q_ws, k_ws, v_ws, o_ws);
    // proj GEMM: M=16384, N=512, K=512 (+bias, fp32 out), 128x64 tiles
    gemm_mfma<1, 64><<<dim3(128, 8), 256, 0, stream>>>(o_ws, pwb, proj_b,
                                                       nullptr, nullptr, nullptr, outp, C_SZ);
}

// Round 7
// 187.581 us; speedup vs baseline: 1.0011x; 1.0011x over previous
//
#include <hip/hip_runtime.h>
#include <hip/hip_bf16.h>

// Problem constants (fixed by setup_inputs)
#define B_SZ 8
#define H_SZ 32     // image rows
#define W_SZ 64     // image cols
#define N_SZ 2048   // H*W
#define C_SZ 512
#define NH 8        // heads
#define HD 64       // head dim
// window 7x11 -> +-3 rows, +-5 cols

using u16 = unsigned short;
typedef __attribute__((ext_vector_type(8))) short s16x8;
typedef __attribute__((ext_vector_type(4))) float f32x4;

__device__ __forceinline__ float bf2f(u16 u) {
    union { unsigned int i; float f; } c; c.i = ((unsigned int)u) << 16; return c.f;
}
__device__ __forceinline__ u16 f2bf(float f) {
    union { float f; unsigned int i; } c; c.f = f;
    unsigned int r = c.i + 0x7fffu + ((c.i >> 16) & 1u);  // RNE
    return (u16)(r >> 16);
}

// async global->LDS, 16B per lane; LDS dest must be wave-uniform base + lane*16
#define GLL16(gp, lp) __builtin_amdgcn_global_load_lds( \
    (const __attribute__((address_space(1))) unsigned int*)(gp), \
    (__attribute__((address_space(3))) unsigned int*)(lp), 16, 0, 0)

// XOR-swizzled 64-elem rows: row = 8 chunks of 8 bf16 (16B); data chunk c of row r
// lives at slot position c ^ (r&7).  Conflict-free ds_read_b128 across l16 lanes.
__device__ __forceinline__ int lds_off(int row, int chunk) {
    return (row * 8 + (chunk ^ (row & 7))) * 8;   // element offset
}

// ---------------- fused fp32 -> bf16 convert (x, qkv_w [q-rows scaled], proj_w) ----
#define NX4 2097152   // x float4 count (16384*512/4)
#define NQ4 196608    // qkv_w float4 count
#define NP4 65536     // proj_w float4 count
__global__ __launch_bounds__(256)
void conv_all(const float* __restrict__ x, const float* __restrict__ qw,
              const float* __restrict__ pw, u16* __restrict__ xb,
              u16* __restrict__ qwb, u16* __restrict__ pwb)
{
    const int i = blockIdx.x * 256 + threadIdx.x;
    const float* src; u16* dst; int idx; float sc = 1.0f;
    if (i < NX4)             { src = x;  dst = xb;  idx = i; }
    else if (i < NX4 + NQ4)  { src = qw; dst = qwb; idx = i - NX4;
                               if (idx < 65536) sc = 0.125f; }  // q-rows: fold 64^-0.5
    else                     { src = pw; dst = pwb; idx = i - NX4 - NQ4; }
    const float4 v = ((const float4*)src)[idx];
    ushort4 o = { f2bf(v.x * sc), f2bf(v.y * sc), f2bf(v.z * sc), f2bf(v.w * sc) };
    ((ushort4*)dst)[idx] = o;
}

// ---------------- MFMA GEMM: C[m,n] = sum_k A[m,k]*Bw[n,k] (bf16, K-contig) ------
// 128xNT tile, BK=64, swizzled LDS. 4 waves in 2x2.  MODE is a template param so
// each instantiation has exactly ONE mfma ordering + ONE epilogue (round-6 lesson:
// a runtime n0 branch kept both paths live -> VGPR 76->116, occupancy cliff).
// MODE 0 (NT=128, grid.y=8):  q/k blocks, SWAPPED mfma(fw,fx) -> D[weight][token],
//                             acc regs d-consecutive -> ushort4 stores to [bh][n][d].
// MODE 2 (NT=128, grid.y=4):  v blocks (n0 base 1024), UNSWAPPED -> D[token][weight],
//                             regs token-consecutive -> ushort4 stores to [bh][d][n].
// MODE 1 (NT=64):             proj, SWAPPED, float4 stores +bias.
template<int MODE, int NT>
__global__ __launch_bounds__(256)
void gemm_mfma(const u16* __restrict__ A, const u16* __restrict__ Bw,
               const float* __restrict__ bias,
               u16* __restrict__ q_ws, u16* __restrict__ k_ws, u16* __restrict__ v_ws,
               float* __restrict__ outp, int K)
{
    constexpr int NJ = (NT == 128) ? 4 : 2;   // 16-row weight tiles per wave
    __shared__ u16 As[128 * 64];
    __shared__ u16 Bs[NT * 64];
    const int t    = threadIdx.x;
    const int m0   = blockIdx.x * 128;
    const int n0   = ((MODE == 2) ? 1024 : 0) + blockIdx.y * NT;
    const int wave = t >> 6, lane = t & 63;
    const int wm   = (wave >> 1) << 6;            // token (m) offset of wave
    const int wn   = (wave & 1) * (NJ * 16);      // weight (n) offset of wave
    const int l16  = lane & 15, quad = lane >> 4;
    const int srow = t >> 3;                    // staging row 0..31 (per 32-row group)
    const int sch  = (t & 7) ^ (srow & 7);      // swizzled data chunk for this slot

    constexpr int AD0 = (MODE == 1) ? 2 : 4;
    f32x4 acc[AD0][4] = {};

    for (int k0 = 0; k0 < K; k0 += 64) {
        __syncthreads();
        #pragma unroll
        for (int g = 0; g < 4; ++g)
            GLL16(A + (size_t)(m0 + 32 * g + srow) * K + k0 + sch * 8,
                  &As[g * 2048 + t * 8]);
        #pragma unroll
        for (int g = 0; g < NT / 32; ++g)
            GLL16(Bw + (size_t)(n0 + 32 * g + srow) * K + k0 + sch * 8,
                  &Bs[g * 2048 + t * 8]);
        __syncthreads();

        s16x8 fx[4][2], fw[NJ][2];
        #pragma unroll
        for (int i = 0; i < 4; ++i) {
            const int R = wm + 16 * i + l16;
            fx[i][0] = *(const s16x8*)&As[lds_off(R, quad)];
            fx[i][1] = *(const s16x8*)&As[lds_off(R, 4 + quad)];
        }
        #pragma unroll
        for (int j = 0; j < NJ; ++j) {
            const int R = wn + 16 * j + l16;
            fw[j][0] = *(const s16x8*)&Bs[lds_off(R, quad)];
            fw[j][1] = *(const s16x8*)&Bs[lds_off(R, 4 + quad)];
        }
        if (MODE != 2) {
            // swapped: acc[w][x] = D[weight][token]
            #pragma unroll
            for (int w = 0; w < AD0; ++w)
                #pragma unroll
                for (int x = 0; x < 4; ++x) {
                    acc[w][x] = __builtin_amdgcn_mfma_f32_16x16x32_bf16(fw[w][0], fx[x][0], acc[w][x], 0, 0, 0);
                    acc[w][x] = __builtin_amdgcn_mfma_f32_16x16x32_bf16(fw[w][1], fx[x][1], acc[w][x], 0, 0, 0);
                }
        } else {
            // V blocks: acc[x][w] = D[token][weight]
            #pragma unroll
            for (int x = 0; x < 4; ++x)
                #pragma unroll
                for (int w = 0; w < 4; ++w) {
                    acc[x][w] = __builtin_amdgcn_mfma_f32_16x16x32_bf16(fx[x][0], fw[w][0], acc[x][w], 0, 0, 0);
                    acc[x][w] = __builtin_amdgcn_mfma_f32_16x16x32_bf16(fx[x][1], fw[w][1], acc[x][w], 0, 0, 0);
                }
        }
    }

    if (MODE == 0) {
        // q/k, swapped: row=weight (d), col=token.  d = 16w + quad*4 + r.
        const int bb = m0 >> 11;                       // batch (block-uniform)
        const int h  = ((n0 + wn) >> 6) & 7;           // wave-uniform head
        u16* T  = (n0 < 512) ? q_ws : k_ws;
        u16* tb = T + ((size_t)bb * NH + h) * (N_SZ * HD);
        const int nn0 = (m0 & 2047) + wm;
        const int dd0 = (quad << 2);
        #pragma unroll
        for (int w = 0; w < 4; ++w)
            #pragma unroll
            for (int x = 0; x < 4; ++x) {
                const int nn = nn0 + 16 * x + l16;
                ushort4 st = { f2bf(acc[w][x][0]), f2bf(acc[w][x][1]),
                               f2bf(acc[w][x][2]), f2bf(acc[w][x][3]) };
                *(ushort4*)(tb + (size_t)nn * HD + 16 * w + dd0) = st;
            }
    } else if (MODE == 2) {
        // V, unswapped: regs are token-consecutive -> [bh][d][n] store
        const int bb  = m0 >> 11;
        const int nnb = (m0 & 2047) + wm + (quad << 2);
        #pragma unroll
        for (int w = 0; w < 4; ++w) {
            const int c = n0 - 1024 + wn + 16 * w + l16;   // v col 0..511
            const int h = c >> 6, dd = c & 63;
            u16* vp = v_ws + (((size_t)bb * NH + h) * HD + dd) * N_SZ + nnb;
            #pragma unroll
            for (int x = 0; x < 4; ++x) {
                ushort4 st = { f2bf(acc[x][w][0]), f2bf(acc[x][w][1]),
                               f2bf(acc[x][w][2]), f2bf(acc[x][w][3]) };
                *(ushort4*)(vp + 16 * x) = st;
            }
        }
    } else {
        // proj, swapped: 4 regs = 4 consecutive out channels -> float4 stores
        #pragma unroll
        for (int w = 0; w < 2; ++w) {
            const int cb = n0 + wn + 16 * w + (quad << 2);
            const float4 bv = *(const float4*)&bias[cb];
            #pragma unroll
            for (int x = 0; x < 4; ++x) {
                const int gm = m0 + wm + 16 * x + l16;
                float4 st = { acc[w][x][0] + bv.x, acc[w][x][1] + bv.y,
                              acc[w][x][2] + bv.z, acc[w][x][3] + bv.w };
                *(float4*)&outp[(size_t)gm * C_SZ + cb] = st;
            }
        }
    }
}

// ---------------- MFMA local attention: 2 image rows / block ----------------
// block = (bh, row-pair p): queries = rows 2p,2p+1 (128 q).  Wave w handles the
// 16-query span [16w,16w+16) in BOTH rows, key window [kb,kb+32),
// kb = clamp(16w-8,0,32).  PV uses the operand swap (O[d][q]) so the final store
// is 8 ushort4 instead of 32 scalar; l transposed across lanes via 8 shfls.
__global__ __launch_bounds__(256)
void attn_mfma(const u16* __restrict__ q_ws, const u16* __restrict__ k_ws,
               const u16* __restrict__ vt_ws, u16* __restrict__ o_ws)
{
    __shared__ u16 KV[2][64 * 64];   // [0]=K row, [1]=Vt row; Q staging at start
    __shared__ u16 Ps[4][16 * 40];   // per-wave P, [q16][key32], stride 40 elems

    const int t = threadIdx.x, wave = t >> 6, lane = t & 63;
    const int l16 = lane & 15, quad = lane >> 4;
    const int u  = blockIdx.x;
    const int p  = u & 15;           // row pair
    const int bh = u >> 4;
    const int r0 = 2 * p, r1 = 2 * p + 1;
    const size_t base = (size_t)bh * (N_SZ * HD);
    const int srow = t >> 3;
    const int sch  = (t & 7) ^ (srow & 7);

    // stage Q rows r0,r1 (128x64 = 16 KB) into KV, swizzled; extract frags
    const u16* qg = q_ws + base + (size_t)r0 * (64 * HD);
    u16* Qst = &KV[0][0];
    #pragma unroll
    for (int g = 0; g < 4; ++g)
        GLL16(qg + (size_t)(srow + 32 * g) * 64 + sch * 8, Qst + g * 2048 + t * 8);
    __syncthreads();

    s16x8 aQ[2][2];
    #pragma unroll
    for (int s = 0; s < 2; ++s) {
        const int Rq = 64 * s + 16 * wave + l16;
        aQ[s][0] = *(const s16x8*)&Qst[lds_off(Rq, quad)];
        aQ[s][1] = *(const s16x8*)&Qst[lds_off(Rq, 4 + quad)];
    }

    const int kb = min(max(16 * wave - 8, 0), 32);   // 0, 8, 24, 32

    f32x4 accO[2][4] = {};
    float lp[2][4] = {};

    const int hlo = (r0 - 3 < 0) ? 0 : r0 - 3;
    const int hhi = (r1 + 3 > H_SZ - 1) ? H_SZ - 1 : r1 + 3;

    for (int hh = hlo; hh <= hhi; ++hh) {
        __syncthreads();   // previous iter's reads (and Q extract) done
        const u16* kg = k_ws + base + (size_t)hh * (64 * HD);
        GLL16(kg + (size_t)srow        * 64 + sch * 8, &KV[0][t * 8]);
        GLL16(kg + (size_t)(srow + 32) * 64 + sch * 8, &KV[0][2048 + t * 8]);
        const u16* vg = vt_ws + base + (size_t)hh * 64;
        GLL16(vg + (size_t)srow        * N_SZ + sch * 8, &KV[1][t * 8]);
        GLL16(vg + (size_t)(srow + 32) * N_SZ + sch * 8, &KV[1][2048 + t * 8]);
        __syncthreads();

        // K/V frags for this wave's 32-key window
        s16x8 bK[2][2];
        #pragma unroll
        for (int j = 0; j < 2; ++j) {
            const int Rk = kb + 16 * j + l16;
            bK[j][0] = *(const s16x8*)&KV[0][lds_off(Rk, quad)];
            bK[j][1] = *(const s16x8*)&KV[0][lds_off(Rk, 4 + quad)];
        }
        s16x8 vf[4];
        #pragma unroll
        for (int j = 0; j < 4; ++j)
            vf[j] = *(const s16x8*)&KV[1][lds_off(16 * j + l16, (kb >> 3) + quad)];

        #pragma unroll
        for (int s = 0; s < 2; ++s) {
            const int dh = hh - (r0 + s);
            if (dh * dh > 9) continue;     // wave-uniform: row out of +-3 range
            f32x4 z[2] = {{0.f,0.f,0.f,0.f},{0.f,0.f,0.f,0.f}};
            #pragma unroll
            for (int j = 0; j < 2; ++j) {
                z[j] = __builtin_amdgcn_mfma_f32_16x16x32_bf16(aQ[s][0], bK[j][0], z[j], 0, 0, 0);
                z[j] = __builtin_amdgcn_mfma_f32_16x16x32_bf16(aQ[s][1], bK[j][1], z[j], 0, 0, 0);
            }
            #pragma unroll
            for (int j = 0; j < 2; ++j) {
                const int ww = kb + 16 * j + l16;   // key w-coord
                #pragma unroll
                for (int r = 0; r < 4; ++r) {
                    const int dw = ww - (16 * wave + quad * 4 + r);
                    const float pv = (dw * dw <= 25) ? __expf(z[j][r]) : 0.f;
                    const u16 pb = f2bf(pv);
                    lp[s][r] += bf2f(pb);
                    Ps[wave][(quad * 4 + r) * 40 + 16 * j + l16] = pb;
                }
            }
            // PV swapped: O[d][q] += V^T(d x key) . P^T(key x q)
            s16x8 aP = *(const s16x8*)&Ps[wave][l16 * 40 + quad * 8];
            #pragma unroll
            for (int j = 0; j < 4; ++j)
                accO[s][j] = __builtin_amdgcn_mfma_f32_16x16x32_bf16(vf[j], aP, accO[s][j], 0, 0, 0);
        }
    }

    // reduce l across the 16 lanes sharing a quad-row (disjoint key subsets)
    #pragma unroll
    for (int s = 0; s < 2; ++s)
        #pragma unroll
        for (int r = 0; r < 4; ++r) {
            lp[s][r] += __shfl_xor(lp[s][r], 1);
            lp[s][r] += __shfl_xor(lp[s][r], 2);
            lp[s][r] += __shfl_xor(lp[s][r], 4);
            lp[s][r] += __shfl_xor(lp[s][r], 8);
        }

    // transpose l: this lane normalizes query q = l16 -> fetch from quad (l16>>2)
    const int srcl = (l16 >> 2) << 4;
    const int rr   = l16 & 3;
    float inv[2];
    #pragma unroll
    for (int s = 0; s < 2; ++s) {
        const float a0 = __shfl(lp[s][0], srcl);
        const float a1 = __shfl(lp[s][1], srcl);
        const float a2 = __shfl(lp[s][2], srcl);
        const float a3 = __shfl(lp[s][3], srcl);
        const float lq = (rr == 0) ? a0 : (rr == 1) ? a1 : (rr == 2) ? a2 : a3;
        inv[s] = 1.0f / lq;
    }

    // write O in (B, N, C) layout: row = query (col l16), 4 regs = 4 consecutive d
    const int bb = bh >> 3, h = bh & 7;
    #pragma unroll
    for (int s = 0; s < 2; ++s) {
        const int row = (r0 + s) * 64 + 16 * wave + l16;
        u16* ob = o_ws + ((size_t)bb * N_SZ + row) * C_SZ + h * 64 + (quad << 2);
        #pragma unroll
        for (int j = 0; j < 4; ++j) {
            ushort4 st = { f2bf(accO[s][j][0] * inv[s]), f2bf(accO[s][j][1] * inv[s]),
                           f2bf(accO[s][j][2] * inv[s]), f2bf(accO[s][j][3] * inv[s]) };
            *(ushort4*)(ob + 16 * j) = st;
        }
    }
}

extern "C" void kernel_launch(void* const* d_in, const int* in_sizes, int n_in,
                              void* d_out, int out_size, void* d_ws, size_t ws_size,
                              hipStream_t stream)
{
    const float* x      = (const float*)d_in[0];
    const float* qkv_w  = (const float*)d_in[1];
    const float* proj_w = (const float*)d_in[2];
    const float* proj_b = (const float*)d_in[3];
    float* outp = (float*)d_out;

    const size_t seg = (size_t)B_SZ * NH * N_SZ * HD;  // 8388608 elems
    u16* q_ws = (u16*)d_ws;
    u16* k_ws = q_ws + seg;
    u16* v_ws = k_ws + seg;      // transposed layout [bh][d][n]
    u16* o_ws = v_ws + seg;
    u16* xb   = o_ws + seg;                       // x as bf16 (8.4M elems)
    u16* qwb  = xb + (size_t)16384 * 512;         // qkv_w bf16 (786432)
    u16* pwb  = qwb + (size_t)1536 * 512;         // proj_w bf16 (262144)

    // one fused convert: (NX4+NQ4+NP4)/256 = 9216 blocks
    conv_all<<<9216, 256, 0, stream>>>(x, qkv_w, proj_w, xb, qwb, pwb);

    // QKV GEMM, split so each kernel has a single compile-time MFMA path:
    //   q/k (swapped):  N-cols [0,1024)
    gemm_mfma<0, 128><<<dim3(128, 8), 256, 0, stream>>>(xb, qwb, nullptr,
                                                        q_ws, k_ws, v_ws, nullptr, C_SZ);
    //   v (unswapped, transposed store): N-cols [1024,1536)
    gemm_mfma<2, 128><<<dim3(128, 4), 256, 0, stream>>>(xb, qwb, nullptr,
                                                        q_ws, k_ws, v_ws, nullptr, C_SZ);
    // local attention, one block per (b,h,row-pair)
    attn_mfma<<<B_SZ * NH * (H_SZ / 2), 256, 0, stream>>>(q_ws, k_ws, v_ws, o_ws);
    // proj GEMM: M=16384, N=512, K=512 (+bias, fp32 out), 128x64 tiles
    gemm_mfma<1, 64><<<dim3(128, 8), 256, 0, stream>>>(o_ws, pwb, proj_b,
                                                       nullptr, nullptr, nullptr, outp, C_SZ);
}